// Round 9
// baseline (305.628 us; speedup 1.0000x reference)
//
#include <hip/hip_runtime.h>

#define N_N 50000
#define N_E 800000
#define NG  128
#define NBKT 782          // ceil(50000/64) buckets of 64 nodes
#define CAP  1536         // slot capacity per bucket (mean 1023, sigma 32)
#define EPB  8192         // edges per k_bin block
#define BINB 98           // ceil(800000/8192)
#define NODE_BLKS 12500   // k_aggc node-blocks (4 nodes/block)

typedef float4 f4;
typedef __attribute__((ext_vector_type(8))) short bf16x8;
typedef __attribute__((ext_vector_type(4))) float f32x4;

__device__ __forceinline__ unsigned short f2b(float x){
  unsigned int u = __float_as_uint(x);
  u += 0x7fffu + ((u >> 16) & 1u);
  return (unsigned short)(u >> 16);
}
__device__ __forceinline__ float b2f(unsigned short h){
  return __uint_as_float(((unsigned int)h) << 16);
}
__device__ __forceinline__ float2 b2f2(unsigned int u){
  float2 r;
  r.x = __uint_as_float(u << 16);
  r.y = __uint_as_float(u & 0xffff0000u);
  return r;
}

// ---------------- init: Wt transpose-cast (blocks 0..127) + zero counters (blocks 128+) ----------------
__global__ __launch_bounds__(256) void k_init(const float* __restrict__ W1, const float* __restrict__ W2,
    unsigned short* __restrict__ Wt1, unsigned short* __restrict__ Wt2,
    int* __restrict__ zp, int n4){
  int i = blockIdx.x*256 + threadIdx.x;
  if (blockIdx.x < 128){
    const float* W = (i < 16384) ? W1 : W2;
    unsigned short* Wt = (i < 16384) ? Wt1 : Wt2;
    int j = i & 16383;
    int k = j >> 7, n = j & 127;
    Wt[n*128 + k] = f2b(W[k*128 + n]);
  } else {
    int z = i - 128*256;
    if (z < n4) zp[z] = 0;
  }
}

// ---------------- block-local counting sort into coarse buckets ----------------
// packs (src<<16 | dst) into u32 (both < 65536)
__global__ __launch_bounds__(512) void k_bin(const int* __restrict__ ei,
    int* __restrict__ bcnt, unsigned int* __restrict__ bins){
  __shared__ unsigned int sorted[EPB];   // 32 KB
  __shared__ int hist[NBKT];
  __shared__ int lstart[NBKT];
  __shared__ int lcur[NBKT];
  __shared__ int gbase[NBKT];
  __shared__ int segsum[16];
  int t = threadIdx.x;
  int e0 = blockIdx.x * EPB;
  int n = N_E - e0; if (n > EPB) n = EPB;
  for (int i=t; i<NBKT; i+=512) hist[i] = 0;
  __syncthreads();
  for (int i=t; i<n; i+=512){
    int d = ei[N_E + e0 + i];
    atomicAdd(&hist[d>>6], 1);
  }
  __syncthreads();
  int w = t >> 6, lane = t & 63;
  for (int seg = w; seg < 13; seg += 8){
    int idx = seg*64 + lane;
    int v = (idx < NBKT) ? hist[idx] : 0;
    int x = v;
    #pragma unroll
    for (int dd=1; dd<64; dd<<=1){ int y = __shfl_up(x, dd, 64); if (lane >= dd) x += y; }
    if (idx < NBKT) lstart[idx] = x - v;
    if (lane == 63) segsum[seg] = x;
  }
  __syncthreads();
  if (t == 0){ int s=0; for (int j=0;j<13;j++){ int v=segsum[j]; segsum[j]=s; s+=v; } }
  __syncthreads();
  for (int i=t; i<NBKT; i+=512){ int v = lstart[i] + segsum[i>>6]; lstart[i] = v; lcur[i] = v; }
  __syncthreads();
  for (int i=t; i<n; i+=512){
    int s = ei[e0 + i], d = ei[N_E + e0 + i];
    int pos = atomicAdd(&lcur[d>>6], 1);
    sorted[pos] = ((unsigned int)s << 16) | (unsigned int)d;
  }
  __syncthreads();
  for (int i=t; i<NBKT; i+=512) gbase[i] = atomicAdd(&bcnt[i], hist[i]);
  __syncthreads();
  for (int i=t; i<n; i+=512){
    unsigned int item = sorted[i];
    int d = item & 0xffff;
    int b = d >> 6;
    bins[b*CAP + gbase[b] + (i - lstart[b])] = item;
  }
}

// ---------------- per-bucket CSR finalize: hist -> scan -> place ----------------
__global__ __launch_bounds__(256) void k_csr(const unsigned int* __restrict__ bins,
    const int* __restrict__ bcnt, int2* __restrict__ sd, float* __restrict__ dinv,
    int* __restrict__ ssrc){
  __shared__ int hist[64];
  __shared__ int lcur[64];
  __shared__ int cnt_s;
  int b = blockIdx.x, t = threadIdx.x;
  if (t < 64) hist[t] = 0;
  if (t == 0) cnt_s = bcnt[b];
  __syncthreads();
  int cnt = cnt_s;
  const unsigned int* P = bins + b*CAP;
  for (int j=t; j<cnt; j+=256) atomicAdd(&hist[P[j] & 63], 1);
  __syncthreads();
  if (t < 64){
    int v = hist[t];
    int x = v;
    #pragma unroll
    for (int dd=1; dd<64; dd<<=1){ int y = __shfl_up(x, dd, 64); if (t >= dd) x += y; }
    int excl = x - v;
    int node = (b<<6) + t;
    if (node < N_N){
      sd[node] = make_int2(b*CAP + excl, v);
      dinv[node] = rsqrtf((float)(v + 1));    // +1 self-loop
    }
    lcur[t] = b*CAP + excl;
  }
  __syncthreads();
  for (int j=t; j<cnt; j+=256){
    unsigned int p = P[j];
    int pos = atomicAdd(&lcur[p & 63], 1);
    ssrc[pos] = (int)(p >> 16);
  }
}

// ---------------- fused add + preprocess MLP (64->128, relu), bf16 chunk-major out ----------------
// out layout: [4][N_N][32] bf16 (chunk-major)
__global__ __launch_bounds__(256) void k_pre(const float* __restrict__ emb, const float* __restrict__ pose,
    const float* __restrict__ W, const float* __restrict__ bias, unsigned short* __restrict__ out){
  __shared__ float As[64*64];
  __shared__ float Bs[64*128];
  int row0 = blockIdx.x*64, tid = threadIdx.x;
  for (int j=tid; j<2048; j+=256) ((f4*)Bs)[j] = ((const f4*)W)[j];
  for (int j=tid; j<1024; j+=256){
    int r = j>>4, c4 = j&15;
    int gr = row0 + r;
    f4 a = {0.f,0.f,0.f,0.f};
    if (gr < N_N){
      f4 e0 = ((const f4*)emb)[gr*16 + c4];
      f4 p0 = ((const f4*)pose)[gr*16 + c4];
      a.x = e0.x+p0.x; a.y = e0.y+p0.y; a.z = e0.z+p0.z; a.w = e0.w+p0.w;
    }
    ((f4*)As)[j] = a;
  }
  __syncthreads();
  int cg = tid&31, rg = tid>>5;
  float acc[8][4] = {};
  for (int k=0;k<64;k++){
    f4 b = ((f4*)Bs)[k*32 + cg];
    #pragma unroll
    for (int i=0;i<8;i++){
      float a = As[(rg*8+i)*64 + k];
      acc[i][0] = fmaf(a,b.x,acc[i][0]); acc[i][1] = fmaf(a,b.y,acc[i][1]);
      acc[i][2] = fmaf(a,b.z,acc[i][2]); acc[i][3] = fmaf(a,b.w,acc[i][3]);
    }
  }
  f4 bb = ((const f4*)bias)[cg];
  int chunk = cg >> 3;                 // features cg*4.. -> chunk
  int coff = (cg & 7) * 4;             // offset within 32-feat chunk
  for (int i=0;i<8;i++){
    int gr = row0 + rg*8 + i;
    if (gr < N_N){
      ushort4 o;
      o.x = f2b(fmaxf(acc[i][0]+bb.x, 0.f));
      o.y = f2b(fmaxf(acc[i][1]+bb.y, 0.f));
      o.z = f2b(fmaxf(acc[i][2]+bb.z, 0.f));
      o.w = f2b(fmaxf(acc[i][3]+bb.w, 0.f));
      *(ushort4*)&out[((size_t)chunk*N_N + gr)*32 + coff] = o;
    }
  }
}

// ---------------- MFMA GEMM: hs = (A @ W) * dinv[row]; A and out chunk-major [4][N_N][32] bf16 ----------------
__global__ __launch_bounds__(256) void k_gemm_mfma(const unsigned short* __restrict__ A,
    const unsigned short* __restrict__ Wt, const float* __restrict__ scale,
    unsigned short* __restrict__ out){
  __shared__ unsigned short Bs[128*128];   // 32 KB, XOR-swizzled [n][k] tiles of 8 bf16
  int tid = threadIdx.x;
  for (int j=tid; j<2048; j+=256){
    int n = j >> 4, c = j & 15;
    ((bf16x8*)Bs)[(n<<4) | (c ^ (n&7))] = ((const bf16x8*)Wt)[j];
  }
  __syncthreads();
  int wid = tid >> 6, l = tid & 63;
  int row0 = blockIdx.x*128 + wid*32;
  int lr = l & 15, kg = l >> 4;
  int ra = row0 + lr;       if (ra > N_N-1) ra = N_N-1;
  int rb = row0 + 16 + lr;  if (rb > N_N-1) rb = N_N-1;
  f32x4 acc[2][8] = {};
  #pragma unroll
  for (int ks=0; ks<4; ks++){
    // chunk-major: chunk ks, within-chunk offset kg*8
    bf16x8 a0 = *(const bf16x8*)&A[((size_t)ks*N_N + ra)*32 + kg*8];
    bf16x8 a1 = *(const bf16x8*)&A[((size_t)ks*N_N + rb)*32 + kg*8];
    #pragma unroll
    for (int nf=0; nf<8; nf++){
      int n = nf*16 + lr;
      bf16x8 b = ((const bf16x8*)Bs)[(n<<4) | ((ks*4+kg) ^ (lr&7))];
      acc[0][nf] = __builtin_amdgcn_mfma_f32_16x16x32_bf16(a0, b, acc[0][nf], 0, 0, 0);
      acc[1][nf] = __builtin_amdgcn_mfma_f32_16x16x32_bf16(a1, b, acc[1][nf], 0, 0, 0);
    }
  }
  #pragma unroll
  for (int mf=0; mf<2; mf++){
    #pragma unroll
    for (int r=0; r<4; r++){
      int R = row0 + mf*16 + (l>>4)*4 + r;
      if (R < N_N){
        float s = scale[R];
        #pragma unroll
        for (int nf=0; nf<8; nf++){
          // output feature n = nf*16+lr -> chunk nf>>1, within-chunk (nf&1)*16+lr
          out[(((size_t)(nf>>1))*N_N + R)*32 + (nf&1)*16 + lr] = f2b(acc[mf][nf][r] * s);
        }
      }
    }
  }
}

// ---------------- chunked edge aggregation ----------------
// grid = 4*NODE_BLKS; chunk = bid/NODE_BLKS so each XCD streams one 3.2MB chunk at a time (L2-resident)
// wave = 1 node, 4 x 16-lane edge groups; out[v] = relu(dinv[v]*(hs[v]+sum hs[src]) + b), chunk-major
__global__ __launch_bounds__(256) void k_aggc(const unsigned int* __restrict__ hbc,  // [4][N_N][16] dwords
    const int2* __restrict__ sd, const int* __restrict__ ssrc, const float* __restrict__ dinv,
    const float* __restrict__ bias, unsigned int* __restrict__ outc){
  int bid = blockIdx.x;
  int chunk = bid / NODE_BLKS;
  int nb = bid - chunk*NODE_BLKS;
  int wid = threadIdx.x >> 6, l = threadIdx.x & 63;
  int v = nb*4 + wid;
  int g = l >> 4, f = l & 15;
  const unsigned int* hc = hbc + (size_t)chunk*N_N*16;
  int2 s_d = sd[v];
  int s = s_d.x, e = s + s_d.y;
  float2 acc = {0.f, 0.f};
  int j = s + g;
  for (; j + 4 < e; j += 8){
    int u0 = __builtin_nontemporal_load(ssrc + j);
    int u1 = __builtin_nontemporal_load(ssrc + j + 4);
    unsigned int m0 = hc[u0*16 + f];
    unsigned int m1 = hc[u1*16 + f];
    float2 f0 = b2f2(m0), f1 = b2f2(m1);
    acc.x += f0.x + f1.x; acc.y += f0.y + f1.y;
  }
  if (j < e){
    float2 m = b2f2(hc[__builtin_nontemporal_load(ssrc + j)*16 + f]);
    acc.x += m.x; acc.y += m.y;
  }
  // combine the 4 groups
  acc.x += __shfl_xor(acc.x, 16, 64); acc.y += __shfl_xor(acc.y, 16, 64);
  acc.x += __shfl_xor(acc.x, 32, 64); acc.y += __shfl_xor(acc.y, 32, 64);
  // self-loop + scale + bias + relu
  float2 sf = b2f2(hc[v*16 + f]);
  acc.x += sf.x; acc.y += sf.y;
  float dv = dinv[v];
  float2 bb = ((const float2*)bias)[chunk*16 + f];
  unsigned int o = (unsigned int)f2b(fmaxf(fmaf(dv, acc.x, bb.x), 0.f))
                 | ((unsigned int)f2b(fmaxf(fmaf(dv, acc.y, bb.y), 0.f)) << 16);
  if (g == 0) __builtin_nontemporal_store(o, &outc[((size_t)chunk*N_N + v)*16 + f]);
}

// ---------------- mean pool over sorted batch (bf16 chunk-major in) ----------------
__global__ __launch_bounds__(128) void k_pool(const unsigned short* __restrict__ x, const int* __restrict__ batch,
    float* __restrict__ gsum, float* __restrict__ gcnt){
  int c = threadIdx.x;
  int cc = c >> 5, w = c & 31;
  const unsigned short* xc = x + (size_t)cc*N_N*32;
  int n0 = blockIdx.x*128;
  int n1 = n0 + 128; if (n1 > N_N) n1 = N_N;
  int cur = batch[n0];
  float acc = 0.f, cnt = 0.f;
  for (int i=n0; i<n1; i++){
    int b = batch[i];
    if (b != cur){
      atomicAdd(&gsum[cur*128+c], acc);
      if (c == 0) atomicAdd(&gcnt[cur], cnt);
      acc = 0.f; cnt = 0.f; cur = b;
    }
    acc += b2f(xc[i*32 + w]);
    cnt += 1.f;
  }
  atomicAdd(&gsum[cur*128+c], acc);
  if (c == 0) atomicAdd(&gcnt[cur], cnt);
}

// ---------------- head MLP (128->64->32, relu both) ----------------
__global__ __launch_bounds__(64) void k_head(const float* __restrict__ gsum, const float* __restrict__ gcnt,
    const float* __restrict__ W1, const float* __restrict__ b1,
    const float* __restrict__ W2, const float* __restrict__ b2, float* __restrict__ out){
  __shared__ float pooled[128];
  __shared__ float h1[64];
  int g = blockIdx.x, t = threadIdx.x;
  float cnt = fmaxf(gcnt[g], 1.f);
  pooled[t]      = gsum[g*128 + t] / cnt;
  pooled[t + 64] = gsum[g*128 + 64 + t] / cnt;
  __syncthreads();
  float a = b1[t];
  for (int k=0; k<128; k++) a = fmaf(pooled[k], W1[k*64 + t], a);
  h1[t] = fmaxf(a, 0.f);
  __syncthreads();
  if (t < 32){
    float o = b2[t];
    for (int k=0; k<64; k++) o = fmaf(h1[k], W2[k*32 + t], o);
    out[g*32 + t] = fmaxf(o, 0.f);
  }
}

extern "C" void kernel_launch(void* const* d_in, const int* in_sizes, int n_in,
                              void* d_out, int out_size, void* d_ws, size_t ws_size,
                              hipStream_t stream){
  const float* emb  = (const float*)d_in[0];
  const float* pose = (const float*)d_in[1];
  const int*   ei   = (const int*)d_in[2];
  const int*   batch= (const int*)d_in[3];
  const float* Wpre = (const float*)d_in[4];
  const float* bpre = (const float*)d_in[5];
  const float* Wg1  = (const float*)d_in[6];
  const float* bg1  = (const float*)d_in[7];
  const float* Wg2  = (const float*)d_in[8];
  const float* bg2  = (const float*)d_in[9];
  const float* Wh1  = (const float*)d_in[10];
  const float* bh1  = (const float*)d_in[11];
  const float* Wh2  = (const float*)d_in[12];
  const float* bh2  = (const float*)d_in[13];
  float* out = (float*)d_out;

  char* ws = (char*)d_ws;
  unsigned short* xb0 = (unsigned short*)(ws + 0);          // 12,800,000 (chunk-major [4][N_N][32])
  unsigned short* xb1 = (unsigned short*)(ws + 12800000);   // 12,800,000
  unsigned short* hb  = (unsigned short*)(ws + 25600000);   // 12,800,000
  unsigned short* Wt1 = (unsigned short*)(ws + 38400000);   // 32,768
  unsigned short* Wt2 = (unsigned short*)(ws + 38432768);   // 32,768
  int2*  sd   = (int2*) (ws + 38465536);   // 400,000
  float* dinv = (float*)(ws + 38865536);   // 200,000
  int*   ssrc = (int*)  (ws + 39065536);   // NBKT*CAP*4 = 4,804,608
  unsigned int* bins = (unsigned int*)(ws + 43870144);   // NBKT*CAP*4 = 4,804,608
  // contiguous zero region: bcnt | gsum | gcnt
  int*   bcnt = (int*)  (ws + 48674752);   // NBKT*4 = 3,128 (pad to 3,136)
  float* gsum = (float*)(ws + 48677888);   // 65,536
  float* gcnt = (float*)(ws + 48743424);   // 512

  const int ZN = (3136 + 65536 + 512) / 4;   // 17,296 ints
  const int ZB = (ZN + 255)/256;             // 68 blocks

  k_init<<<128 + ZB, 256, 0, stream>>>(Wg1, Wg2, Wt1, Wt2, bcnt, ZN);

  k_bin<<<BINB, 512, 0, stream>>>(ei, bcnt, bins);
  k_csr<<<NBKT, 256, 0, stream>>>(bins, bcnt, sd, dinv, ssrc);

  k_pre<<<(N_N+63)/64, 256, 0, stream>>>(emb, pose, Wpre, bpre, xb0);             // x1 -> xb0

  k_gemm_mfma<<<(N_N+127)/128, 256, 0, stream>>>(xb0, Wt1, dinv, hb);             // hs1 -> hb
  k_aggc<<<4*NODE_BLKS, 256, 0, stream>>>((const unsigned int*)hb, sd, ssrc, dinv, bg1, (unsigned int*)xb1);

  k_gemm_mfma<<<(N_N+127)/128, 256, 0, stream>>>(xb1, Wt2, dinv, hb);             // hs2 -> hb
  k_aggc<<<4*NODE_BLKS, 256, 0, stream>>>((const unsigned int*)hb, sd, ssrc, dinv, bg2, (unsigned int*)xb0);

  k_pool<<<(N_N+127)/128, 128, 0, stream>>>(xb0, batch, gsum, gcnt);
  k_head<<<NG, 64, 0, stream>>>(gsum, gcnt, Wh1, bh1, Wh2, bh2, out);
}